// Round 3
// baseline (233.201 us; speedup 1.0000x reference)
//
#include <hip/hip_runtime.h>
#include <hip/hip_bf16.h>
#include <stdint.h>

// ContextualLoss forward, MI355X. B=4, C=256, N=4096.
// S[n,m] = <Xc[:,n],Yc[:,m]> / (|Xc_n||Yc_m|); A_max[n] = 1/sum_m exp(beta_n (S-smax_n));
// beta_n = 10/(1.001 - smax_n); loss_b = -log(mean_n A_max).
// GEMM on centered UNnormalized bf16; norms folded into epilogue.
// R2: A-operand in 128 VGPRs (no A LDS traffic), triple-buffered Y staging,
// counted vmcnt(6) never-0 pipeline, 2 sub-phases/tile, setprio on MFMA.

#define Bn 4
#define Cn 256
#define Nn 4096

typedef float  f32x16 __attribute__((ext_vector_type(16)));
typedef __bf16 bf16x8 __attribute__((ext_vector_type(8)));

#define GLD16(gp, lp) __builtin_amdgcn_global_load_lds(                      \
    (const __attribute__((address_space(1))) void*)(gp),                     \
    (__attribute__((address_space(3))) void*)(lp), 16, 0, 0)

#define LDbf(base, off) (*(const bf16x8*)((base) + (off)))
#define MFMA32(a, b, c) __builtin_amdgcn_mfma_f32_32x32x16_bf16((a), (b), (c), 0, 0, 0)

// ---------- K1: per-(b,c) spatial mean of Y ----------
__global__ __launch_bounds__(256) void k_mean(const float* __restrict__ Y,
                                              float* __restrict__ ymean) {
  const int bc = blockIdx.x;                       // 0..1023
  const float4* p4 = (const float4*)(Y + (size_t)bc * 4096);
  float s = 0.f;
  #pragma unroll
  for (int i = 0; i < 4; ++i) {
    float4 v = p4[threadIdx.x + i * 256];
    s += (v.x + v.y) + (v.z + v.w);
  }
  #pragma unroll
  for (int m = 1; m < 64; m <<= 1) s += __shfl_xor(s, m);
  __shared__ float part[4];
  if ((threadIdx.x & 63) == 0) part[threadIdx.x >> 6] = s;
  __syncthreads();
  if (threadIdx.x == 0)
    ymean[bc] = (part[0] + part[1] + part[2] + part[3]) * (1.0f / 4096.0f);
}

// ---------- K2: center, transpose [C][N]->[N][C], cast bf16, inv-norms ----------
// Block = 64 n x all 256 c. Norm^2 accumulated per-thread in read phase
// (thread (tc,tn) owns channels cc*64+4i+tc for spatial tn) -> 4-way LDS combine.
__global__ __launch_bounds__(256) void k_pack(const float* __restrict__ X,
                                              const float* __restrict__ Y,
                                              const float* __restrict__ ymean,
                                              __hip_bfloat16* __restrict__ Xp,
                                              __hip_bfloat16* __restrict__ Yp,
                                              float* __restrict__ invnx,
                                              float* __restrict__ invny) {
  const int n0 = blockIdx.x * 64, b = blockIdx.y;
  __shared__ float mu[256];
  __shared__ float tile[64][65];
  __shared__ float part[8][64];
  const int t  = threadIdx.x;
  const int tc = t >> 6, tn = t & 63;              // read: 4 c-rows x 64 n
  const int oc = t & 63, on = t >> 6;              // write: 64 c, 4 n-rows
  mu[t] = ymean[b * 256 + t];
  __syncthreads();
  float psx = 0.f, psy = 0.f;
  for (int cc = 0; cc < 4; ++cc) {
    #pragma unroll 4
    for (int i = 0; i < 16; ++i) {
      int cl = i * 4 + tc;
      float v = X[((size_t)b * 256 + cc * 64 + cl) * 4096 + n0 + tn] - mu[cc * 64 + cl];
      tile[cl][tn] = v;
      psx += v * v;
    }
    __syncthreads();
    #pragma unroll 4
    for (int i = 0; i < 16; ++i) {
      int nl = i * 4 + on;
      Xp[((size_t)b * 4096 + n0 + nl) * 256 + cc * 64 + oc] = __float2bfloat16(tile[oc][nl]);
    }
    __syncthreads();
    #pragma unroll 4
    for (int i = 0; i < 16; ++i) {
      int cl = i * 4 + tc;
      float v = Y[((size_t)b * 256 + cc * 64 + cl) * 4096 + n0 + tn] - mu[cc * 64 + cl];
      tile[cl][tn] = v;
      psy += v * v;
    }
    __syncthreads();
    #pragma unroll 4
    for (int i = 0; i < 16; ++i) {
      int nl = i * 4 + on;
      Yp[((size_t)b * 4096 + n0 + nl) * 256 + cc * 64 + oc] = __float2bfloat16(tile[oc][nl]);
    }
    __syncthreads();
  }
  part[tc][tn] = psx;
  part[4 + tc][tn] = psy;
  __syncthreads();
  if (t < 64)
    invnx[b * 4096 + n0 + t] = rsqrtf(part[0][t] + part[1][t] + part[2][t] + part[3][t]);
  else if (t < 128) {
    int u = t - 64;
    invny[b * 4096 + n0 + u] = rsqrtf(part[4][u] + part[5][u] + part[6][u] + part[7][u]);
  }
}

// ---------- K3: GEMM pass kernel (PASS=1 rowmax, PASS=2 expsum) ----------
// 256 blocks (1/CU): block = 128 rows x 2048 cols, K=256. 8 waves (2rg x 4cs),
// wave tile 64x64 per 256-col macro-tile, 32x32x16 MFMA.
// A (64 rows x K=256 per wave) lives in 128 VGPRs, loaded once from global.
// Y triple-buffered [256m][128B k] (3x32KB), swizzle (m&7)<<4 on source+read.
// Tile p: {stage half(p+2); vmcnt(6); s_barrier; [4 ds_read; stage half; 8 MFMA]x2;
//          harvest if kp==3; s_barrier}. Tail peeled with vmcnt(4)/(0).
template<int PASS>
__global__ __launch_bounds__(512, 2) void k_pass(const __hip_bfloat16* __restrict__ Xp,
                                                 const __hip_bfloat16* __restrict__ Yp,
                                                 const float* __restrict__ invnx,
                                                 const float* __restrict__ invny,
                                                 float* __restrict__ rmax_part,
                                                 float* __restrict__ ssum_part) {
  __shared__ __align__(16) char YsL[3][32768];        // [m][128B k], swz (m&7)<<4
  __shared__ float invnyL[2048];
  __shared__ float redm[2][2][2][16][4];              // [rg][hi][ai][reg][cs]
  __shared__ float2 lammuL[128];

  const int tid = threadIdx.x;
  const int lane = tid & 63;
  const int w = tid >> 6;
  const int rg = w >> 2, cs = w & 3;
  const int l31 = lane & 31, hi = lane >> 5;
  const int hi16 = hi << 4;

  // block decode: XCD (=L%8) owns one (b,half) Y panel (1MB) for L2 locality
  const int L = blockIdx.x;
  const int b = (L & 7) >> 1, half = L & 1;
  const int rowtile = L >> 3;                         // [0,32)
  const int rowg0 = b * Nn + rowtile * 128;
  const int colg0 = half * 2048;

  const char* Xgb = (const char*)Xp + (size_t)rowg0 * 512;
  const char* Yg  = (const char*)(Yp + ((size_t)b * Nn + colg0) * Cn);

  // --- A operand -> registers (per wave: rows rg*64+{l31, l31+32}, full K) ---
  bf16x8 A[4][4][2];                                  // [kp][s][ai], all static idx
  #pragma unroll
  for (int kp = 0; kp < 4; ++kp)
    #pragma unroll
    for (int s = 0; s < 4; ++s)
      #pragma unroll
      for (int ai = 0; ai < 2; ++ai)
        A[kp][s][ai] = *(const bf16x8*)(Xgb + (size_t)(rg * 64 + ai * 32 + l31) * 512
                                            + ((kp * 4 + s) * 32 + hi16));

  // --- prologue LDS fills (before any GLD16 so vmcnt counts stay pure) ---
  ((float4*)invnyL)[tid] = ((const float4*)(invny + b * Nn + colg0))[tid];
  if constexpr (PASS == 2) {
    if (tid < 128) {
      int rowg = rowg0 + tid;
      float mg = fmaxf(rmax_part[rowg], rmax_part[Bn * Nn + rowg]);
      float ix = invnx[rowg];
      float smax = mg * ix;
      float lam = (10.0f / (1.001f - smax)) * ix * 1.44269504f;
      lammuL[tid] = make_float2(lam, lam * mg);
    }
  }
  __syncthreads();

  // --- staging offsets (pre-swizzled global source, linear LDS dest) ---
  int yoff[4];
  #pragma unroll
  for (int i = 0; i < 4; ++i) {
    int m = i * 64 + (tid >> 3);
    yoff[i] = m * 512 + (((tid & 7) * 16) ^ ((m & 7) << 4));
  }

#define STAGE_HALF(q, h)                                                      \
  { const int q_ = (q);                                                       \
    const char* src_ = Yg + (size_t)((q_ >> 2) * 131072 + (q_ & 3) * 128);    \
    char* dst_ = YsL[q_ % 3];                                                 \
    GLD16(src_ + yoff[2 * (h)],     dst_ + (2 * (h)) * 8192 + tid * 16);      \
    GLD16(src_ + yoff[2 * (h) + 1], dst_ + (2 * (h) + 1) * 8192 + tid * 16); }

  STAGE_HALF(0, 0); STAGE_HALF(0, 1);
  STAGE_HALF(1, 0); STAGE_HALF(1, 1);

  const int brow0 = cs * 64 + l31;
  const int bswz  = (brow0 & 7) << 4;

  f32x16 acc[2][2];
  #pragma unroll
  for (int ai = 0; ai < 2; ++ai)
    #pragma unroll
    for (int bj = 0; bj < 2; ++bj) acc[ai][bj] = (f32x16)0.0f;
  float accR[2][16];                                  // PASS1: rowmax, PASS2: expsum
  #pragma unroll
  for (int ai = 0; ai < 2; ++ai)
    #pragma unroll
    for (int r = 0; r < 16; ++r) accR[ai][r] = (PASS == 1) ? -3.0e38f : 0.f;

#define HARVEST()                                                             \
  { const int cb = mt * 256 + cs * 64 + l31;                                  \
    const float iny0 = invnyL[cb], iny1 = invnyL[cb + 32];                    \
    _Pragma("unroll")                                                         \
    for (int ai = 0; ai < 2; ++ai) {                                          \
      _Pragma("unroll")                                                       \
      for (int r = 0; r < 16; ++r) {                                          \
        if constexpr (PASS == 1) {                                            \
          accR[ai][r] = fmaxf(accR[ai][r],                                    \
              fmaxf(acc[ai][0][r] * iny0, acc[ai][1][r] * iny1));             \
        } else {                                                              \
          float2 lm = lammuL[rg * 64 + ai * 32 + (r & 3) + 8 * (r >> 2) + 4 * hi]; \
          accR[ai][r] += exp2f(fmaf(lm.x, acc[ai][0][r] * iny0, -lm.y))       \
                       + exp2f(fmaf(lm.x, acc[ai][1][r] * iny1, -lm.y));      \
        }                                                                     \
        acc[ai][0][r] = 0.f; acc[ai][1][r] = 0.f;                             \
      } } }

#define TILE(KP, WAITS, DO_STAGE)                                             \
  { const int p_ = mt * 4 + (KP);                                             \
    if (DO_STAGE) STAGE_HALF(p_ + 2, 0);                                      \
    asm volatile("s_waitcnt vmcnt(" WAITS ")" ::: "memory");                  \
    asm volatile("s_barrier" ::: "memory");                                   \
    const char* yb_ = YsL[p_ % 3];                                            \
    bf16x8 b00 = LDbf(yb_, brow0 * 128 + ((0 + hi16) ^ bswz));                \
    bf16x8 b01 = LDbf(yb_, (brow0 + 32) * 128 + ((0 + hi16) ^ bswz));         \
    bf16x8 b10 = LDbf(yb_, brow0 * 128 + ((32 + hi16) ^ bswz));               \
    bf16x8 b11 = LDbf(yb_, (brow0 + 32) * 128 + ((32 + hi16) ^ bswz));        \
    if (DO_STAGE) STAGE_HALF(p_ + 2, 1);                                      \
    __builtin_amdgcn_s_setprio(1);                                            \
    acc[0][0] = MFMA32(A[KP][0][0], b00, acc[0][0]);                          \
    acc[0][1] = MFMA32(A[KP][0][0], b01, acc[0][1]);                          \
    acc[1][0] = MFMA32(A[KP][0][1], b00, acc[1][0]);                          \
    acc[1][1] = MFMA32(A[KP][0][1], b01, acc[1][1]);                          \
    acc[0][0] = MFMA32(A[KP][1][0], b10, acc[0][0]);                          \
    acc[0][1] = MFMA32(A[KP][1][0], b11, acc[0][1]);                          \
    acc[1][0] = MFMA32(A[KP][1][1], b10, acc[1][0]);                          \
    acc[1][1] = MFMA32(A[KP][1][1], b11, acc[1][1]);                          \
    __builtin_amdgcn_s_setprio(0);                                            \
    bf16x8 b20 = LDbf(yb_, brow0 * 128 + ((64 + hi16) ^ bswz));               \
    bf16x8 b21 = LDbf(yb_, (brow0 + 32) * 128 + ((64 + hi16) ^ bswz));        \
    bf16x8 b30 = LDbf(yb_, brow0 * 128 + ((96 + hi16) ^ bswz));               \
    bf16x8 b31 = LDbf(yb_, (brow0 + 32) * 128 + ((96 + hi16) ^ bswz));        \
    __builtin_amdgcn_s_setprio(1);                                            \
    acc[0][0] = MFMA32(A[KP][2][0], b20, acc[0][0]);                          \
    acc[0][1] = MFMA32(A[KP][2][0], b21, acc[0][1]);                          \
    acc[1][0] = MFMA32(A[KP][2][1], b20, acc[1][0]);                          \
    acc[1][1] = MFMA32(A[KP][2][1], b21, acc[1][1]);                          \
    acc[0][0] = MFMA32(A[KP][3][0], b30, acc[0][0]);                          \
    acc[0][1] = MFMA32(A[KP][3][0], b31, acc[0][1]);                          \
    acc[1][0] = MFMA32(A[KP][3][1], b30, acc[1][0]);                          \
    acc[1][1] = MFMA32(A[KP][3][1], b31, acc[1][1]);                          \
    __builtin_amdgcn_s_setprio(0);                                            \
    if ((KP) == 3) HARVEST();                                                 \
    asm volatile("s_barrier" ::: "memory"); }

  // main loop: tiles 0..27, uniform counted vmcnt(6)
  for (int mt = 0; mt < 7; ++mt) {
    TILE(0, "6", true)
    TILE(1, "6", true)
    TILE(2, "6", true)
    TILE(3, "6", true)
  }
  // peeled tail mt=7: p=28 stages 30, p=29 stages 31, p=30/31 drain
  {
    const int mt = 7;
    TILE(0, "6", true)
    TILE(1, "6", true)
    TILE(2, "4", false)
    TILE(3, "0", false)
  }
#undef TILE
#undef HARVEST
#undef STAGE_HALF

  // --- epilogue: reduce 32 col-lanes, across cs-waves, write global ---
  #pragma unroll
  for (int ai = 0; ai < 2; ++ai)
    #pragma unroll
    for (int r = 0; r < 16; ++r) {
      float v = accR[ai][r];
      #pragma unroll
      for (int m = 1; m < 32; m <<= 1) {
        float o = __shfl_xor(v, m);
        v = (PASS == 1) ? fmaxf(v, o) : (v + o);
      }
      if (l31 == 0) redm[rg][hi][ai][r][cs] = v;
    }
  __syncthreads();
  if (tid < 128) {
    const int rgg = tid >> 6, rr = tid & 63;
    const int aii = (rr >> 5) & 1, r32 = rr & 31;
    const int hh = (r32 >> 2) & 1;
    const int reg = (r32 & 3) | (((r32 >> 3) & 3) << 2);
    float v0 = redm[rgg][hh][aii][reg][0], v1 = redm[rgg][hh][aii][reg][1];
    float v2 = redm[rgg][hh][aii][reg][2], v3 = redm[rgg][hh][aii][reg][3];
    if constexpr (PASS == 1)
      rmax_part[half * (Bn * Nn) + rowg0 + tid] = fmaxf(fmaxf(v0, v1), fmaxf(v2, v3));
    else
      ssum_part[half * (Bn * Nn) + rowg0 + tid] = v0 + v1 + v2 + v3;
  }
}

// ---------- K4: loss = -log(mean_n 1/(ssum0+ssum1)) ----------
__global__ __launch_bounds__(256) void k_fin(const float* __restrict__ ssum_part,
                                             float* __restrict__ out) {
  const int b = blockIdx.x;
  float s = 0.f;
  #pragma unroll 4
  for (int i = 0; i < 16; ++i) {
    int row = b * Nn + threadIdx.x + i * 256;
    s += 1.0f / (ssum_part[row] + ssum_part[Bn * Nn + row]);
  }
  #pragma unroll
  for (int m = 1; m < 64; m <<= 1) s += __shfl_xor(s, m);
  __shared__ float part[4];
  if ((threadIdx.x & 63) == 0) part[threadIdx.x >> 6] = s;
  __syncthreads();
  if (threadIdx.x == 0)
    out[b] = -logf((part[0] + part[1] + part[2] + part[3]) * (1.0f / (float)Nn));
}

extern "C" void kernel_launch(void* const* d_in, const int* in_sizes, int n_in,
                              void* d_out, int out_size, void* d_ws, size_t ws_size,
                              hipStream_t stream) {
  const float* X = (const float*)d_in[0];
  const float* Y = (const float*)d_in[1];
  float* out = (float*)d_out;
  char* ws = (char*)d_ws;

  // workspace layout (~17.2 MB)
  __hip_bfloat16* Xp = (__hip_bfloat16*)ws;                       // 8MB [B][N][C]
  __hip_bfloat16* Yp = (__hip_bfloat16*)(ws + 8388608);           // 8MB
  float* invnx = (float*)(ws + 16777216);                         // 16384 f32
  float* invny = invnx + 16384;                                   // 16384 f32
  float* rmax  = invny + 16384;                                   // [2][16384] f32
  float* ssum  = rmax + 32768;                                    // [2][16384] f32
  float* ymean = ssum + 32768;                                    // 1024 f32

  k_mean  <<<Bn * Cn, 256, 0, stream>>>(Y, ymean);
  k_pack  <<<dim3(Nn / 64, Bn), 256, 0, stream>>>(X, Y, ymean, Xp, Yp, invnx, invny);
  k_pass<1><<<256, 512, 0, stream>>>(Xp, Yp, invnx, invny, rmax, ssum);
  k_pass<2><<<256, 512, 0, stream>>>(Xp, Yp, invnx, invny, rmax, ssum);
  k_fin   <<<Bn, 256, 0, stream>>>(ssum, out);
}

// Round 4
// 228.854 us; speedup vs baseline: 1.0190x; 1.0190x over previous
//
#include <hip/hip_runtime.h>
#include <hip/hip_bf16.h>
#include <stdint.h>

// ContextualLoss forward, MI355X. B=4, C=256, N=4096.
// S[n,m] = <Xc[:,n],Yc[:,m]> / (|Xc_n||Yc_m|); A_max[n] = 1/sum_m exp(beta_n (S-smax_n));
// beta_n = 10/(1.001 - smax_n); loss_b = -log(mean_n A_max).
// GEMM on centered UNnormalized bf16; norms folded into epilogue.
// R3: fix R2's spill — __launch_bounds__(512,1) so the unified reg budget is
// 256/wave (R2's (512,2) meant 2 blocks/CU -> 128-reg cap -> 15MB scratch).
// A-operand in 128 VGPRs, triple-buffered Y staging, counted vmcnt(6),
// pairwise B-loads (8 live B regs), setprio around MFMA quads.

#define Bn 4
#define Cn 256
#define Nn 4096

typedef float  f32x16 __attribute__((ext_vector_type(16)));
typedef __bf16 bf16x8 __attribute__((ext_vector_type(8)));

#define GLD16(gp, lp) __builtin_amdgcn_global_load_lds(                      \
    (const __attribute__((address_space(1))) void*)(gp),                     \
    (__attribute__((address_space(3))) void*)(lp), 16, 0, 0)

#define LDbf(base, off) (*(const bf16x8*)((base) + (off)))
#define MFMA32(a, b, c) __builtin_amdgcn_mfma_f32_32x32x16_bf16((a), (b), (c), 0, 0, 0)

// ---------- K1: per-(b,c) spatial mean of Y ----------
__global__ __launch_bounds__(256) void k_mean(const float* __restrict__ Y,
                                              float* __restrict__ ymean) {
  const int bc = blockIdx.x;                       // 0..1023
  const float4* p4 = (const float4*)(Y + (size_t)bc * 4096);
  float s = 0.f;
  #pragma unroll
  for (int i = 0; i < 4; ++i) {
    float4 v = p4[threadIdx.x + i * 256];
    s += (v.x + v.y) + (v.z + v.w);
  }
  #pragma unroll
  for (int m = 1; m < 64; m <<= 1) s += __shfl_xor(s, m);
  __shared__ float part[4];
  if ((threadIdx.x & 63) == 0) part[threadIdx.x >> 6] = s;
  __syncthreads();
  if (threadIdx.x == 0)
    ymean[bc] = (part[0] + part[1] + part[2] + part[3]) * (1.0f / 4096.0f);
}

// ---------- K2: center, transpose [C][N]->[N][C], cast bf16, inv-norms ----------
__global__ __launch_bounds__(256) void k_pack(const float* __restrict__ X,
                                              const float* __restrict__ Y,
                                              const float* __restrict__ ymean,
                                              __hip_bfloat16* __restrict__ Xp,
                                              __hip_bfloat16* __restrict__ Yp,
                                              float* __restrict__ invnx,
                                              float* __restrict__ invny) {
  const int n0 = blockIdx.x * 64, b = blockIdx.y;
  __shared__ float mu[256];
  __shared__ float tile[64][65];
  __shared__ float part[8][64];
  const int t  = threadIdx.x;
  const int tc = t >> 6, tn = t & 63;              // read: 4 c-rows x 64 n
  const int oc = t & 63, on = t >> 6;              // write: 64 c, 4 n-rows
  mu[t] = ymean[b * 256 + t];
  __syncthreads();
  float psx = 0.f, psy = 0.f;
  for (int cc = 0; cc < 4; ++cc) {
    #pragma unroll 4
    for (int i = 0; i < 16; ++i) {
      int cl = i * 4 + tc;
      float v = X[((size_t)b * 256 + cc * 64 + cl) * 4096 + n0 + tn] - mu[cc * 64 + cl];
      tile[cl][tn] = v;
      psx += v * v;
    }
    __syncthreads();
    #pragma unroll 4
    for (int i = 0; i < 16; ++i) {
      int nl = i * 4 + on;
      Xp[((size_t)b * 4096 + n0 + nl) * 256 + cc * 64 + oc] = __float2bfloat16(tile[oc][nl]);
    }
    __syncthreads();
    #pragma unroll 4
    for (int i = 0; i < 16; ++i) {
      int cl = i * 4 + tc;
      float v = Y[((size_t)b * 256 + cc * 64 + cl) * 4096 + n0 + tn] - mu[cc * 64 + cl];
      tile[cl][tn] = v;
      psy += v * v;
    }
    __syncthreads();
    #pragma unroll 4
    for (int i = 0; i < 16; ++i) {
      int nl = i * 4 + on;
      Yp[((size_t)b * 4096 + n0 + nl) * 256 + cc * 64 + oc] = __float2bfloat16(tile[oc][nl]);
    }
    __syncthreads();
  }
  part[tc][tn] = psx;
  part[4 + tc][tn] = psy;
  __syncthreads();
  if (t < 64)
    invnx[b * 4096 + n0 + t] = rsqrtf(part[0][t] + part[1][t] + part[2][t] + part[3][t]);
  else if (t < 128) {
    int u = t - 64;
    invny[b * 4096 + n0 + u] = rsqrtf(part[4][u] + part[5][u] + part[6][u] + part[7][u]);
  }
}

// ---------- K3: GEMM pass kernel (PASS=1 rowmax, PASS=2 expsum) ----------
// 256 blocks (1/CU): block = 128 rows x 2048 cols, K=256. 8 waves (2rg x 4cs),
// wave tile 64x64 per 256-col macro-tile, 32x32x16 MFMA.
// A (64 rows x K=256 per wave) lives in 128 VGPRs, loaded once from global.
// Y triple-buffered [256m][128B k] (3x32KB), swizzle (m&7)<<4 on source+read.
// Tile p: {stage half(p+2); vmcnt(6); s_barrier; 4x[2 ds_read; 4 MFMA];
//          harvest if kp==3; s_barrier}. Tail peeled with vmcnt(4)/(0).
template<int PASS>
__global__ __launch_bounds__(512, 1) void k_pass(const __hip_bfloat16* __restrict__ Xp,
                                                 const __hip_bfloat16* __restrict__ Yp,
                                                 const float* __restrict__ invnx,
                                                 const float* __restrict__ invny,
                                                 float* __restrict__ rmax_part,
                                                 float* __restrict__ ssum_part) {
  __shared__ __align__(16) char YsL[3][32768];        // [m][128B k], swz (m&7)<<4
  __shared__ float invnyL[2048];
  __shared__ float redm[2][2][2][16][4];              // [rg][hi][ai][reg][cs]
  __shared__ float2 lammuL[128];

  const int tid = threadIdx.x;
  const int lane = tid & 63;
  const int w = tid >> 6;
  const int rg = w >> 2, cs = w & 3;
  const int l31 = lane & 31, hi = lane >> 5;
  const int hi16 = hi << 4;

  // block decode: XCD (=L%8) owns one (b,half) Y panel (1MB) for L2 locality
  const int L = blockIdx.x;
  const int b = (L & 7) >> 1, half = L & 1;
  const int rowtile = L >> 3;                         // [0,32)
  const int rowg0 = b * Nn + rowtile * 128;
  const int colg0 = half * 2048;

  const char* Xgb = (const char*)Xp + (size_t)rowg0 * 512;
  const char* Yg  = (const char*)(Yp + ((size_t)b * Nn + colg0) * Cn);

  // --- A operand -> registers (per wave: rows rg*64+{l31, l31+32}, full K) ---
  bf16x8 A[4][4][2];                                  // [kp][s][ai], all static idx
  #pragma unroll
  for (int kp = 0; kp < 4; ++kp)
    #pragma unroll
    for (int s = 0; s < 4; ++s)
      #pragma unroll
      for (int ai = 0; ai < 2; ++ai)
        A[kp][s][ai] = *(const bf16x8*)(Xgb + (size_t)(rg * 64 + ai * 32 + l31) * 512
                                            + ((kp * 4 + s) * 32 + hi16));

  // --- prologue LDS fills (before any GLD16 so vmcnt counts stay pure) ---
  ((float4*)invnyL)[tid] = ((const float4*)(invny + b * Nn + colg0))[tid];
  if constexpr (PASS == 2) {
    if (tid < 128) {
      int rowg = rowg0 + tid;
      float mg = fmaxf(rmax_part[rowg], rmax_part[Bn * Nn + rowg]);
      float ix = invnx[rowg];
      float smax = mg * ix;
      float lam = (10.0f / (1.001f - smax)) * ix * 1.44269504f;
      lammuL[tid] = make_float2(lam, lam * mg);
    }
  }
  __syncthreads();

  // --- staging offsets (pre-swizzled global source, linear LDS dest) ---
  int yoff[4];
  #pragma unroll
  for (int i = 0; i < 4; ++i) {
    int m = i * 64 + (tid >> 3);
    yoff[i] = m * 512 + (((tid & 7) * 16) ^ ((m & 7) << 4));
  }

#define STAGE_HALF(q, h)                                                      \
  { const int q_ = (q);                                                       \
    const char* src_ = Yg + (size_t)((q_ >> 2) * 131072 + (q_ & 3) * 128);    \
    char* dst_ = YsL[q_ % 3];                                                 \
    GLD16(src_ + yoff[2 * (h)],     dst_ + (2 * (h)) * 8192 + tid * 16);      \
    GLD16(src_ + yoff[2 * (h) + 1], dst_ + (2 * (h) + 1) * 8192 + tid * 16); }

  STAGE_HALF(0, 0); STAGE_HALF(0, 1);
  STAGE_HALF(1, 0); STAGE_HALF(1, 1);

  const int brow0 = cs * 64 + l31;
  const int bswz  = (brow0 & 7) << 4;

  f32x16 acc[2][2];
  #pragma unroll
  for (int ai = 0; ai < 2; ++ai)
    #pragma unroll
    for (int bj = 0; bj < 2; ++bj) acc[ai][bj] = (f32x16)0.0f;
  float accR[2][16];                                  // PASS1: rowmax, PASS2: expsum
  #pragma unroll
  for (int ai = 0; ai < 2; ++ai)
    #pragma unroll
    for (int r = 0; r < 16; ++r) accR[ai][r] = (PASS == 1) ? -3.0e38f : 0.f;

#define HARVEST()                                                             \
  { const int cb = mt * 256 + cs * 64 + l31;                                  \
    const float iny0 = invnyL[cb], iny1 = invnyL[cb + 32];                    \
    _Pragma("unroll")                                                         \
    for (int ai = 0; ai < 2; ++ai) {                                          \
      _Pragma("unroll")                                                       \
      for (int r = 0; r < 16; ++r) {                                          \
        if constexpr (PASS == 1) {                                            \
          accR[ai][r] = fmaxf(accR[ai][r],                                    \
              fmaxf(acc[ai][0][r] * iny0, acc[ai][1][r] * iny1));             \
        } else {                                                              \
          float2 lm = lammuL[rg * 64 + ai * 32 + (r & 3) + 8 * (r >> 2) + 4 * hi]; \
          accR[ai][r] += exp2f(fmaf(lm.x, acc[ai][0][r] * iny0, -lm.y))       \
                       + exp2f(fmaf(lm.x, acc[ai][1][r] * iny1, -lm.y));      \
        }                                                                     \
        acc[ai][0][r] = 0.f; acc[ai][1][r] = 0.f;                             \
      } } }

#define QUAD(KP, S, KB)                                                       \
  { bf16x8 b0_ = LDbf(yb_, brow0 * 128 + (((KB) + hi16) ^ bswz));             \
    bf16x8 b1_ = LDbf(yb_, (brow0 + 32) * 128 + (((KB) + hi16) ^ bswz));      \
    __builtin_amdgcn_s_setprio(1);                                            \
    acc[0][0] = MFMA32(A[KP][S][0], b0_, acc[0][0]);                          \
    acc[0][1] = MFMA32(A[KP][S][0], b1_, acc[0][1]);                          \
    acc[1][0] = MFMA32(A[KP][S][1], b0_, acc[1][0]);                          \
    acc[1][1] = MFMA32(A[KP][S][1], b1_, acc[1][1]);                          \
    __builtin_amdgcn_s_setprio(0); }

#define TILE(KP, WAITS, DO_STAGE)                                             \
  { const int p_ = mt * 4 + (KP);                                             \
    if (DO_STAGE) STAGE_HALF(p_ + 2, 0);                                      \
    asm volatile("s_waitcnt vmcnt(" WAITS ")" ::: "memory");                  \
    asm volatile("s_barrier" ::: "memory");                                   \
    const char* yb_ = YsL[p_ % 3];                                            \
    QUAD(KP, 0, 0)                                                            \
    QUAD(KP, 1, 32)                                                           \
    if (DO_STAGE) STAGE_HALF(p_ + 2, 1);                                      \
    QUAD(KP, 2, 64)                                                           \
    QUAD(KP, 3, 96)                                                           \
    if ((KP) == 3) HARVEST();                                                 \
    asm volatile("s_barrier" ::: "memory"); }

  // main loop: tiles 0..27, uniform counted vmcnt(6)
  for (int mt = 0; mt < 7; ++mt) {
    TILE(0, "6", true)
    TILE(1, "6", true)
    TILE(2, "6", true)
    TILE(3, "6", true)
  }
  // peeled tail mt=7: p=28 stages 30, p=29 stages 31, p=30/31 drain
  {
    const int mt = 7;
    TILE(0, "6", true)
    TILE(1, "6", true)
    TILE(2, "4", false)
    TILE(3, "0", false)
  }
#undef TILE
#undef QUAD
#undef HARVEST
#undef STAGE_HALF

  // --- epilogue: reduce 32 col-lanes, across cs-waves, write global ---
  #pragma unroll
  for (int ai = 0; ai < 2; ++ai)
    #pragma unroll
    for (int r = 0; r < 16; ++r) {
      float v = accR[ai][r];
      #pragma unroll
      for (int m = 1; m < 32; m <<= 1) {
        float o = __shfl_xor(v, m);
        v = (PASS == 1) ? fmaxf(v, o) : (v + o);
      }
      if (l31 == 0) redm[rg][hi][ai][r][cs] = v;
    }
  __syncthreads();
  if (tid < 128) {
    const int rgg = tid >> 6, rr = tid & 63;
    const int aii = (rr >> 5) & 1, r32 = rr & 31;
    const int hh = (r32 >> 2) & 1;
    const int reg = (r32 & 3) | (((r32 >> 3) & 3) << 2);
    float v0 = redm[rgg][hh][aii][reg][0], v1 = redm[rgg][hh][aii][reg][1];
    float v2 = redm[rgg][hh][aii][reg][2], v3 = redm[rgg][hh][aii][reg][3];
    if constexpr (PASS == 1)
      rmax_part[half * (Bn * Nn) + rowg0 + tid] = fmaxf(fmaxf(v0, v1), fmaxf(v2, v3));
    else
      ssum_part[half * (Bn * Nn) + rowg0 + tid] = v0 + v1 + v2 + v3;
  }
}

// ---------- K4: loss = -log(mean_n 1/(ssum0+ssum1)) ----------
__global__ __launch_bounds__(256) void k_fin(const float* __restrict__ ssum_part,
                                             float* __restrict__ out) {
  const int b = blockIdx.x;
  float s = 0.f;
  #pragma unroll 4
  for (int i = 0; i < 16; ++i) {
    int row = b * Nn + threadIdx.x + i * 256;
    s += 1.0f / (ssum_part[row] + ssum_part[Bn * Nn + row]);
  }
  #pragma unroll
  for (int m = 1; m < 64; m <<= 1) s += __shfl_xor(s, m);
  __shared__ float part[4];
  if ((threadIdx.x & 63) == 0) part[threadIdx.x >> 6] = s;
  __syncthreads();
  if (threadIdx.x == 0)
    out[b] = -logf((part[0] + part[1] + part[2] + part[3]) * (1.0f / (float)Nn));
}

extern "C" void kernel_launch(void* const* d_in, const int* in_sizes, int n_in,
                              void* d_out, int out_size, void* d_ws, size_t ws_size,
                              hipStream_t stream) {
  const float* X = (const float*)d_in[0];
  const float* Y = (const float*)d_in[1];
  float* out = (float*)d_out;
  char* ws = (char*)d_ws;

  // workspace layout (~17.2 MB)
  __hip_bfloat16* Xp = (__hip_bfloat16*)ws;                       // 8MB [B][N][C]
  __hip_bfloat16* Yp = (__hip_bfloat16*)(ws + 8388608);           // 8MB
  float* invnx = (float*)(ws + 16777216);                         // 16384 f32
  float* invny = invnx + 16384;                                   // 16384 f32
  float* rmax  = invny + 16384;                                   // [2][16384] f32
  float* ssum  = rmax + 32768;                                    // [2][16384] f32
  float* ymean = ssum + 32768;                                    // 1024 f32

  k_mean  <<<Bn * Cn, 256, 0, stream>>>(Y, ymean);
  k_pack  <<<dim3(Nn / 64, Bn), 256, 0, stream>>>(X, Y, ymean, Xp, Yp, invnx, invny);
  k_pass<1><<<256, 512, 0, stream>>>(Xp, Yp, invnx, invny, rmax, ssum);
  k_pass<2><<<256, 512, 0, stream>>>(Xp, Yp, invnx, invny, rmax, ssum);
  k_fin   <<<Bn, 256, 0, stream>>>(ssum, out);
}

// Round 5
// 200.550 us; speedup vs baseline: 1.1628x; 1.1411x over previous
//
#include <hip/hip_runtime.h>
#include <hip/hip_bf16.h>
#include <stdint.h>

// ContextualLoss forward, MI355X. B=4, C=256, N=4096.
// S[n,m] = <Xc[:,n],Yc[:,m]> / (|Xc_n||Yc_m|); A_max[n] = 1/sum_m exp(beta_n (S-smax_n));
// beta_n = 10/(1.001 - smax_n); loss_b = -log(mean_n A_max).
// R4: kill the spill (R2/R3: VGPR cap 128, 8.8-15MB scratch). A operand split:
// k-phases {0,1} in 64 VGPRs, {2,3} in a 32KB LDS tile. Occupancy pinned via
// amdgpu_waves_per_eu(2,2) -> 256-reg budget. Schedule (triple-buffered Y,
// counted vmcnt(6), setprio MFMA quads) unchanged from R3 (absmax 0 twice).

#define Bn 4
#define Cn 256
#define Nn 4096

typedef float  f32x16 __attribute__((ext_vector_type(16)));
typedef __bf16 bf16x8 __attribute__((ext_vector_type(8)));

#define GLD16(gp, lp) __builtin_amdgcn_global_load_lds(                      \
    (const __attribute__((address_space(1))) void*)(gp),                     \
    (__attribute__((address_space(3))) void*)(lp), 16, 0, 0)

#define LDbf(base, off) (*(const bf16x8*)((base) + (off)))
#define MFMA32(a, b, c) __builtin_amdgcn_mfma_f32_32x32x16_bf16((a), (b), (c), 0, 0, 0)

// ---------- K1: per-(b,c) spatial mean of Y ----------
__global__ __launch_bounds__(256) void k_mean(const float* __restrict__ Y,
                                              float* __restrict__ ymean) {
  const int bc = blockIdx.x;                       // 0..1023
  const float4* p4 = (const float4*)(Y + (size_t)bc * 4096);
  float s = 0.f;
  #pragma unroll
  for (int i = 0; i < 4; ++i) {
    float4 v = p4[threadIdx.x + i * 256];
    s += (v.x + v.y) + (v.z + v.w);
  }
  #pragma unroll
  for (int m = 1; m < 64; m <<= 1) s += __shfl_xor(s, m);
  __shared__ float part[4];
  if ((threadIdx.x & 63) == 0) part[threadIdx.x >> 6] = s;
  __syncthreads();
  if (threadIdx.x == 0)
    ymean[bc] = (part[0] + part[1] + part[2] + part[3]) * (1.0f / 4096.0f);
}

// ---------- K2: center, transpose [C][N]->[N][C], cast bf16, inv-norms ----------
__global__ __launch_bounds__(256) void k_pack(const float* __restrict__ X,
                                              const float* __restrict__ Y,
                                              const float* __restrict__ ymean,
                                              __hip_bfloat16* __restrict__ Xp,
                                              __hip_bfloat16* __restrict__ Yp,
                                              float* __restrict__ invnx,
                                              float* __restrict__ invny) {
  const int n0 = blockIdx.x * 64, b = blockIdx.y;
  __shared__ float mu[256];
  __shared__ float tile[64][65];
  __shared__ float part[8][64];
  const int t  = threadIdx.x;
  const int tc = t >> 6, tn = t & 63;              // read: 4 c-rows x 64 n
  const int oc = t & 63, on = t >> 6;              // write: 64 c, 4 n-rows
  mu[t] = ymean[b * 256 + t];
  __syncthreads();
  float psx = 0.f, psy = 0.f;
  for (int cc = 0; cc < 4; ++cc) {
    #pragma unroll 4
    for (int i = 0; i < 16; ++i) {
      int cl = i * 4 + tc;
      float v = X[((size_t)b * 256 + cc * 64 + cl) * 4096 + n0 + tn] - mu[cc * 64 + cl];
      tile[cl][tn] = v;
      psx += v * v;
    }
    __syncthreads();
    #pragma unroll 4
    for (int i = 0; i < 16; ++i) {
      int nl = i * 4 + on;
      Xp[((size_t)b * 4096 + n0 + nl) * 256 + cc * 64 + oc] = __float2bfloat16(tile[oc][nl]);
    }
    __syncthreads();
    #pragma unroll 4
    for (int i = 0; i < 16; ++i) {
      int cl = i * 4 + tc;
      float v = Y[((size_t)b * 256 + cc * 64 + cl) * 4096 + n0 + tn] - mu[cc * 64 + cl];
      tile[cl][tn] = v;
      psy += v * v;
    }
    __syncthreads();
    #pragma unroll 4
    for (int i = 0; i < 16; ++i) {
      int nl = i * 4 + on;
      Yp[((size_t)b * 4096 + n0 + nl) * 256 + cc * 64 + oc] = __float2bfloat16(tile[oc][nl]);
    }
    __syncthreads();
  }
  part[tc][tn] = psx;
  part[4 + tc][tn] = psy;
  __syncthreads();
  if (t < 64)
    invnx[b * 4096 + n0 + t] = rsqrtf(part[0][t] + part[1][t] + part[2][t] + part[3][t]);
  else if (t < 128) {
    int u = t - 64;
    invny[b * 4096 + n0 + u] = rsqrtf(part[4][u] + part[5][u] + part[6][u] + part[7][u]);
  }
}

// ---------- K3: GEMM pass kernel (PASS=1 rowmax, PASS=2 expsum) ----------
// 256 blocks (1/CU): block = 128 rows x 2048 cols, K=256. 8 waves (2rg x 4cs),
// wave tile 64x64 per 256-col macro-tile, 32x32x16 MFMA.
// A: k in [0,128) -> 64 VGPRs (loaded once); k in [128,256) -> 32KB LDS tile
// [128 rows][256B], swizzle (row&7)<<4 on source+read, staged once.
// Y triple-buffered [256m][128B k] (3x32KB), same swizzle.
// Tile p: {stage half(p+2); vmcnt(6); s_barrier; 4x[ds_reads; 4 MFMA];
//          harvest if kp==3; s_barrier}. Tail peeled with vmcnt(4)/(0).
template<int PASS>
__global__ __launch_bounds__(512)
__attribute__((amdgpu_waves_per_eu(2, 2)))
void k_pass(const __hip_bfloat16* __restrict__ Xp,
            const __hip_bfloat16* __restrict__ Yp,
            const float* __restrict__ invnx,
            const float* __restrict__ invny,
            float* __restrict__ rmax_part,
            float* __restrict__ ssum_part) {
  __shared__ __align__(16) char YsL[3][32768];        // [m][128B k], swz (m&7)<<4
  __shared__ __align__(16) char AsL[32768];           // [128 r][256B k-hi], swz (r&7)<<4
  __shared__ float invnyL[2048];
  __shared__ float redm[2][2][2][16][4];              // [rg][hi][ai][reg][cs]
  __shared__ float2 lammuL[128];

  const int tid = threadIdx.x;
  const int lane = tid & 63;
  const int w = tid >> 6;
  const int rg = w >> 2, cs = w & 3;
  const int l31 = lane & 31, hi = lane >> 5;
  const int hi16 = hi << 4;

  // block decode: XCD (=L%8) owns one (b,half) Y panel (1MB) for L2 locality
  const int L = blockIdx.x;
  const int b = (L & 7) >> 1, half = L & 1;
  const int rowtile = L >> 3;                         // [0,32)
  const int rowg0 = b * Nn + rowtile * 128;
  const int colg0 = half * 2048;

  const char* Xgb = (const char*)Xp + (size_t)rowg0 * 512;
  const char* Yg  = (const char*)(Yp + ((size_t)b * Nn + colg0) * Cn);

  // --- A low half (k in [0,128)) -> 64 VGPRs (16 global_load_dwordx4) ---
  bf16x8 A[2][4][2];                                  // [kp][s][ai], static idx
  #pragma unroll
  for (int kp = 0; kp < 2; ++kp)
    #pragma unroll
    for (int s = 0; s < 4; ++s)
      #pragma unroll
      for (int ai = 0; ai < 2; ++ai)
        A[kp][s][ai] = *(const bf16x8*)(Xgb + (size_t)(rg * 64 + ai * 32 + l31) * 512
                                            + ((kp * 4 + s) * 32 + hi16));

  // --- prologue LDS fills (plain LDS writes, no vmcnt) ---
  ((float4*)invnyL)[tid] = ((const float4*)(invny + b * Nn + colg0))[tid];
  if constexpr (PASS == 2) {
    if (tid < 128) {
      int rowg = rowg0 + tid;
      float mg = fmaxf(rmax_part[rowg], rmax_part[Bn * Nn + rowg]);
      float ix = invnx[rowg];
      float smax = mg * ix;
      float lam = (10.0f / (1.001f - smax)) * ix * 1.44269504f;
      lammuL[tid] = make_float2(lam, lam * mg);
    }
  }
  __syncthreads();

  // --- stage A high half (k in [128,256)) to AsL: 4 GLD16/thread ---
  #pragma unroll
  for (int s = 0; s < 4; ++s) {
    const int off = s * 8192 + tid * 16;
    const int row = off >> 8;                         // 256B rows
    const int col = off & 255;
    GLD16(Xgb + (size_t)row * 512 + 256 + (col ^ ((row & 7) << 4)), AsL + off);
  }

  // --- Y staging offsets (pre-swizzled global source, linear LDS dest) ---
  int yoff[4];
  #pragma unroll
  for (int i = 0; i < 4; ++i) {
    int m = i * 64 + (tid >> 3);
    yoff[i] = m * 512 + (((tid & 7) * 16) ^ ((m & 7) << 4));
  }

#define STAGE_HALF(q, h)                                                      \
  { const int q_ = (q);                                                       \
    const char* src_ = Yg + (size_t)((q_ >> 2) * 131072 + (q_ & 3) * 128);    \
    char* dst_ = YsL[q_ % 3];                                                 \
    GLD16(src_ + yoff[2 * (h)],     dst_ + (2 * (h)) * 8192 + tid * 16);      \
    GLD16(src_ + yoff[2 * (h) + 1], dst_ + (2 * (h) + 1) * 8192 + tid * 16); }

  STAGE_HALF(0, 0); STAGE_HALF(0, 1);
  STAGE_HALF(1, 0); STAGE_HALF(1, 1);

  const int brow0 = cs * 64 + l31;
  const int bswz  = (brow0 & 7) << 4;
  const int arow0 = rg * 64 + l31;                    // A-LDS row (+ai*32)
  const int aswz  = (l31 & 7) << 4;

  f32x16 acc[2][2];
  #pragma unroll
  for (int ai = 0; ai < 2; ++ai)
    #pragma unroll
    for (int bj = 0; bj < 2; ++bj) acc[ai][bj] = (f32x16)0.0f;
  float accR[2][16];                                  // PASS1: rowmax, PASS2: expsum
  #pragma unroll
  for (int ai = 0; ai < 2; ++ai)
    #pragma unroll
    for (int r = 0; r < 16; ++r) accR[ai][r] = (PASS == 1) ? -3.0e38f : 0.f;

#define HARVEST()                                                             \
  { const int cb = mt * 256 + cs * 64 + l31;                                  \
    const float iny0 = invnyL[cb], iny1 = invnyL[cb + 32];                    \
    _Pragma("unroll")                                                         \
    for (int ai = 0; ai < 2; ++ai) {                                          \
      _Pragma("unroll")                                                       \
      for (int r = 0; r < 16; ++r) {                                          \
        if constexpr (PASS == 1) {                                            \
          accR[ai][r] = fmaxf(accR[ai][r],                                    \
              fmaxf(acc[ai][0][r] * iny0, acc[ai][1][r] * iny1));             \
        } else {                                                              \
          float2 lm = lammuL[rg * 64 + ai * 32 + (r & 3) + 8 * (r >> 2) + 4 * hi]; \
          accR[ai][r] += exp2f(fmaf(lm.x, acc[ai][0][r] * iny0, -lm.y))       \
                       + exp2f(fmaf(lm.x, acc[ai][1][r] * iny1, -lm.y));      \
        }                                                                     \
        acc[ai][0][r] = 0.f; acc[ai][1][r] = 0.f;                             \
      } } }

// QUAD_R: A from VGPRs (kp 0,1). QUAD_L: A from AsL (kp 2,3).
#define QUAD_R(KP, S, KB)                                                     \
  { bf16x8 b0_ = LDbf(yb_, brow0 * 128 + (((KB) + hi16) ^ bswz));             \
    bf16x8 b1_ = LDbf(yb_, (brow0 + 32) * 128 + (((KB) + hi16) ^ bswz));      \
    __builtin_amdgcn_s_setprio(1);                                            \
    acc[0][0] = MFMA32(A[KP][S][0], b0_, acc[0][0]);                          \
    acc[0][1] = MFMA32(A[KP][S][0], b1_, acc[0][1]);                          \
    acc[1][0] = MFMA32(A[KP][S][1], b0_, acc[1][0]);                          \
    acc[1][1] = MFMA32(A[KP][S][1], b1_, acc[1][1]);                          \
    __builtin_amdgcn_s_setprio(0); }

#define QUAD_L(KP, S, KB)                                                     \
  { const int ka_ = (((KP) - 2) * 4 + (S)) * 32 + hi16;                       \
    bf16x8 a0_ = LDbf(AsL, arow0 * 256 + (ka_ ^ aswz));                       \
    bf16x8 a1_ = LDbf(AsL, (arow0 + 32) * 256 + (ka_ ^ aswz));                \
    bf16x8 b0_ = LDbf(yb_, brow0 * 128 + (((KB) + hi16) ^ bswz));             \
    bf16x8 b1_ = LDbf(yb_, (brow0 + 32) * 128 + (((KB) + hi16) ^ bswz));      \
    __builtin_amdgcn_s_setprio(1);                                            \
    acc[0][0] = MFMA32(a0_, b0_, acc[0][0]);                                  \
    acc[0][1] = MFMA32(a0_, b1_, acc[0][1]);                                  \
    acc[1][0] = MFMA32(a1_, b0_, acc[1][0]);                                  \
    acc[1][1] = MFMA32(a1_, b1_, acc[1][1]);                                  \
    __builtin_amdgcn_s_setprio(0); }

#define TILE_HEAD(KP, WAITS, DO_STAGE)                                        \
    const int p_ = mt * 4 + (KP);                                             \
    if (DO_STAGE) STAGE_HALF(p_ + 2, 0);                                      \
    asm volatile("s_waitcnt vmcnt(" WAITS ")" ::: "memory");                  \
    asm volatile("s_barrier" ::: "memory");                                   \
    const char* yb_ = YsL[p_ % 3];

#define TILE_R(KP, WAITS, DO_STAGE)                                           \
  { TILE_HEAD(KP, WAITS, DO_STAGE)                                            \
    QUAD_R(KP, 0, 0)                                                          \
    QUAD_R(KP, 1, 32)                                                         \
    if (DO_STAGE) STAGE_HALF(p_ + 2, 1);                                      \
    QUAD_R(KP, 2, 64)                                                         \
    QUAD_R(KP, 3, 96)                                                         \
    asm volatile("s_barrier" ::: "memory"); }

#define TILE_L(KP, WAITS, DO_STAGE)                                           \
  { TILE_HEAD(KP, WAITS, DO_STAGE)                                            \
    QUAD_L(KP, 0, 0)                                                          \
    QUAD_L(KP, 1, 32)                                                         \
    if (DO_STAGE) STAGE_HALF(p_ + 2, 1);                                      \
    QUAD_L(KP, 2, 64)                                                         \
    QUAD_L(KP, 3, 96)                                                         \
    if ((KP) == 3) HARVEST();                                                 \
    asm volatile("s_barrier" ::: "memory"); }

  // main loop: tiles 0..27, uniform counted vmcnt(6)
  for (int mt = 0; mt < 7; ++mt) {
    TILE_R(0, "6", true)
    TILE_R(1, "6", true)
    TILE_L(2, "6", true)
    TILE_L(3, "6", true)
  }
  // peeled tail mt=7: p=28 stages 30, p=29 stages 31, p=30/31 drain
  {
    const int mt = 7;
    TILE_R(0, "6", true)
    TILE_R(1, "6", true)
    TILE_L(2, "4", false)
    TILE_L(3, "0", false)
  }
#undef TILE_R
#undef TILE_L
#undef TILE_HEAD
#undef QUAD_R
#undef QUAD_L
#undef HARVEST
#undef STAGE_HALF

  // --- epilogue: reduce 32 col-lanes, across cs-waves, write global ---
  #pragma unroll
  for (int ai = 0; ai < 2; ++ai)
    #pragma unroll
    for (int r = 0; r < 16; ++r) {
      float v = accR[ai][r];
      #pragma unroll
      for (int m = 1; m < 32; m <<= 1) {
        float o = __shfl_xor(v, m);
        v = (PASS == 1) ? fmaxf(v, o) : (v + o);
      }
      if (l31 == 0) redm[rg][hi][ai][r][cs] = v;
    }
  __syncthreads();
  if (tid < 128) {
    const int rgg = tid >> 6, rr = tid & 63;
    const int aii = (rr >> 5) & 1, r32 = rr & 31;
    const int hh = (r32 >> 2) & 1;
    const int reg = (r32 & 3) | (((r32 >> 3) & 3) << 2);
    float v0 = redm[rgg][hh][aii][reg][0], v1 = redm[rgg][hh][aii][reg][1];
    float v2 = redm[rgg][hh][aii][reg][2], v3 = redm[rgg][hh][aii][reg][3];
    if constexpr (PASS == 1)
      rmax_part[half * (Bn * Nn) + rowg0 + tid] = fmaxf(fmaxf(v0, v1), fmaxf(v2, v3));
    else
      ssum_part[half * (Bn * Nn) + rowg0 + tid] = v0 + v1 + v2 + v3;
  }
}

// ---------- K4: loss = -log(mean_n 1/(ssum0+ssum1)) ----------
__global__ __launch_bounds__(256) void k_fin(const float* __restrict__ ssum_part,
                                             float* __restrict__ out) {
  const int b = blockIdx.x;
  float s = 0.f;
  #pragma unroll 4
  for (int i = 0; i < 16; ++i) {
    int row = b * Nn + threadIdx.x + i * 256;
    s += 1.0f / (ssum_part[row] + ssum_part[Bn * Nn + row]);
  }
  #pragma unroll
  for (int m = 1; m < 64; m <<= 1) s += __shfl_xor(s, m);
  __shared__ float part[4];
  if ((threadIdx.x & 63) == 0) part[threadIdx.x >> 6] = s;
  __syncthreads();
  if (threadIdx.x == 0)
    out[b] = -logf((part[0] + part[1] + part[2] + part[3]) * (1.0f / (float)Nn));
}

extern "C" void kernel_launch(void* const* d_in, const int* in_sizes, int n_in,
                              void* d_out, int out_size, void* d_ws, size_t ws_size,
                              hipStream_t stream) {
  const float* X = (const float*)d_in[0];
  const float* Y = (const float*)d_in[1];
  float* out = (float*)d_out;
  char* ws = (char*)d_ws;

  // workspace layout (~17.2 MB)
  __hip_bfloat16* Xp = (__hip_bfloat16*)ws;                       // 8MB [B][N][C]
  __hip_bfloat16* Yp = (__hip_bfloat16*)(ws + 8388608);           // 8MB
  float* invnx = (float*)(ws + 16777216);                         // 16384 f32
  float* invny = invnx + 16384;                                   // 16384 f32
  float* rmax  = invny + 16384;                                   // [2][16384] f32
  float* ssum  = rmax + 32768;                                    // [2][16384] f32
  float* ymean = ssum + 32768;                                    // 1024 f32

  k_mean  <<<Bn * Cn, 256, 0, stream>>>(Y, ymean);
  k_pack  <<<dim3(Nn / 64, Bn), 256, 0, stream>>>(X, Y, ymean, Xp, Yp, invnx, invny);
  k_pass<1><<<256, 512, 0, stream>>>(Xp, Yp, invnx, invny, rmax, ssum);
  k_pass<2><<<256, 512, 0, stream>>>(Xp, Yp, invnx, invny, rmax, ssum);
  k_fin   <<<Bn, 256, 0, stream>>>(ssum, out);
}